// Round 1
// baseline (726.011 us; speedup 1.0000x reference)
//
#include <hip/hip_runtime.h>
#include <math.h>

#define BB 4
#define VV 1024
#define DD 3
#define HH 128
#define H2 (HH / 2)
#define EE ((VV * (VV - 1)) / 2)   // 523776
#define NTHR 256

// ---------------------------------------------------------------------------
// Round 1: vector-fp32 baseline. Thread per (batch, edge). Weights in LDS.
// h1 is streamed (one k at a time) so only h2[64] lives in registers.
// ---------------------------------------------------------------------------
__global__ __launch_bounds__(NTHR) void edge_mlp_kernel(
    const float* __restrict__ vertices,  // [B, V, 3]
    const float* __restrict__ W1,        // [6, 128]
    const float* __restrict__ b1,        // [128]
    const float* __restrict__ W2,        // [128, 64]
    const float* __restrict__ b2,        // [64]
    const float* __restrict__ W3,        // [64]
    const float* __restrict__ b3,        // [1]
    float* __restrict__ out)             // [B*E probs][E*2 indices-as-float]
{
    __shared__ float sW1[6 * HH];
    __shared__ float sb1[HH];
    __shared__ float sW2[HH][H2];
    __shared__ float sb2[H2];
    __shared__ float sW3[H2];
    __shared__ float sb3;

    for (int idx = threadIdx.x; idx < 6 * HH; idx += NTHR) sW1[idx] = W1[idx];
    for (int idx = threadIdx.x; idx < HH;     idx += NTHR) sb1[idx] = b1[idx];
    for (int idx = threadIdx.x; idx < HH * H2; idx += NTHR)
        sW2[idx / H2][idx % H2] = W2[idx];
    for (int idx = threadIdx.x; idx < H2; idx += NTHR) sb2[idx] = b2[idx];
    for (int idx = threadIdx.x; idx < H2; idx += NTHR) sW3[idx] = W3[idx];
    if (threadIdx.x == 0) sb3 = b3[0];
    __syncthreads();

    // B*E = 2095104 = 8184 * 256 exactly: no tail check needed.
    long long t = (long long)blockIdx.x * NTHR + threadIdx.x;
    int b = (int)(t / EE);
    int e = (int)(t % EE);

    // Decode e -> (i, j), i < j, row-major triangular order:
    //   start(i) = i*(2V - i - 1)/2 ; j = e - start(i) + i + 1
    double tv = 2.0 * (double)VV - 1.0;
    int i = (int)((tv - sqrt(tv * tv - 8.0 * (double)e)) * 0.5);
    if (i < 0) i = 0;
    if (i > VV - 2) i = VV - 2;
    // robust fixup for any sqrt rounding
    while (i > 0 && (long long)i * (2 * VV - i - 1) / 2 > e) --i;
    while ((long long)(i + 1) * (2 * VV - (i + 1) - 1) / 2 <= e) ++i;
    int j = e - (int)((long long)i * (2 * VV - i - 1) / 2) + i + 1;

    const float* vi = vertices + ((long long)b * VV + i) * DD;
    const float* vj = vertices + ((long long)b * VV + j) * DD;
    float f0 = vi[0], f1 = vi[1], f2 = vi[2];
    float f3 = vj[0], f4 = vj[1], f5 = vj[2];

    float h2a[H2];
#pragma unroll
    for (int n = 0; n < H2; ++n) h2a[n] = sb2[n];

    for (int k = 0; k < HH; ++k) {
        float h = sb1[k];
        h = fmaf(f0, sW1[0 * HH + k], h);
        h = fmaf(f1, sW1[1 * HH + k], h);
        h = fmaf(f2, sW1[2 * HH + k], h);
        h = fmaf(f3, sW1[3 * HH + k], h);
        h = fmaf(f4, sW1[4 * HH + k], h);
        h = fmaf(f5, sW1[5 * HH + k], h);
        h = fmaxf(h, 0.0f);
        const float4* w2row = (const float4*)(&sW2[k][0]);
#pragma unroll
        for (int n4 = 0; n4 < H2 / 4; ++n4) {
            float4 w = w2row[n4];
            h2a[4 * n4 + 0] = fmaf(h, w.x, h2a[4 * n4 + 0]);
            h2a[4 * n4 + 1] = fmaf(h, w.y, h2a[4 * n4 + 1]);
            h2a[4 * n4 + 2] = fmaf(h, w.z, h2a[4 * n4 + 2]);
            h2a[4 * n4 + 3] = fmaf(h, w.w, h2a[4 * n4 + 3]);
        }
    }

    float acc = sb3;
#pragma unroll
    for (int n = 0; n < H2; ++n)
        acc = fmaf(fmaxf(h2a[n], 0.0f), sW3[n], acc);

    float prob = 1.0f / (1.0f + expf(-acc));

    out[(long long)b * EE + e] = prob;
    if (b == 0) {
        out[(long long)BB * EE + 2LL * e]     = (float)i;
        out[(long long)BB * EE + 2LL * e + 1] = (float)j;
    }
}

extern "C" void kernel_launch(void* const* d_in, const int* in_sizes, int n_in,
                              void* d_out, int out_size, void* d_ws, size_t ws_size,
                              hipStream_t stream) {
    const float* vertices = (const float*)d_in[0];
    const float* W1 = (const float*)d_in[1];
    const float* b1 = (const float*)d_in[2];
    const float* W2 = (const float*)d_in[3];
    const float* b2 = (const float*)d_in[4];
    const float* W3 = (const float*)d_in[5];
    const float* b3 = (const float*)d_in[6];
    float* out = (float*)d_out;

    const long long total = (long long)BB * EE;   // 2095104
    const int grid = (int)(total / NTHR);         // 8184, exact

    edge_mlp_kernel<<<grid, NTHR, 0, stream>>>(vertices, W1, b1, W2, b2, W3, b3, out);
}

// Round 2
// 207.387 us; speedup vs baseline: 3.5008x; 3.5008x over previous
//
#include <hip/hip_runtime.h>
#include <hip/hip_bf16.h>
#include <math.h>

#define BB 4
#define VV 1024
#define HH 128
#define H2 64
#define EE 523776               // V*(V-1)/2
#define BE (BB * EE)            // 2095104
#define NTILES (BE / 16)        // 130944 (exact)
#define NTHR 256
#define NBLK 1024

typedef __attribute__((ext_vector_type(8))) short bf16x8;
typedef __attribute__((ext_vector_type(4))) float f32x4;

__device__ __forceinline__ short f2bf(float f) {
    __hip_bfloat16 h = __float2bfloat16(f);
    return *reinterpret_cast<short*>(&h);
}

// ---------------------------------------------------------------------------
// Round 2: bf16 MFMA. Per wave, 16 edges/iter.
//  L1 (swapped): D1[h][e] = W1pad^T[128x32] . feats^T[32x16]   (8 MFMA 16x16x32)
//     bias b1 folded into K-slot 6 (feat[6]=1).
//  relu -> bf16 -> 4KB per-wave LDS bounce (XOR-16B swizzle) -> B-frags
//  L2 (swapped): D2[n2][e] = W2^T[64x128] . h1[128x16]        (16 MFMA)
//  L3: per-lane 16 fma with W3, shfl_xor(16,32) reduce, sigmoid.
// Weights live in constant VGPR A-frags (W1T: 8 frags, W2T: 16 frags).
// ---------------------------------------------------------------------------
__global__ __launch_bounds__(NTHR, 2) void edge_mlp_mfma(
    const float* __restrict__ vertices,  // [4,1024,3]
    const float* __restrict__ W1,        // [6,128]
    const float* __restrict__ b1,        // [128]
    const float* __restrict__ W2,        // [128,64]
    const float* __restrict__ b2,        // [64]
    const float* __restrict__ W3,        // [64]
    const float* __restrict__ b3,        // [1]
    float* __restrict__ out)             // [BE probs][2*EE indices-as-float]
{
    __shared__ float sv[BB * VV * 3];                        // 48 KB vertices
    __shared__ __align__(16) unsigned short h1s[4][16 * HH]; // 4 KB per wave

    const int lane = threadIdx.x & 63;
    const int wid  = threadIdx.x >> 6;
    const int col  = lane & 15;   // edge slot / fragment row (lane&15)
    const int u    = lane >> 4;   // 4 lane-groups

    // ---- stage vertices to LDS (float4, coalesced) ----
    {
        const float4* v4 = (const float4*)vertices;
        float4* s4 = (float4*)sv;
        for (int idx = threadIdx.x; idx < (BB * VV * 3) / 4; idx += NTHR)
            s4[idx] = v4[idx];
    }

    // ---- constant A-fragments in VGPRs ----
    // L1: A1[t] = W1pad^T tile t: A[row=col -> h=16t+col][k=8u+r]
    bf16x8 A1[8];
#pragma unroll
    for (int t = 0; t < 8; ++t) {
        int h = 16 * t + col;
#pragma unroll
        for (int r = 0; r < 8; ++r) {
            int k = 8 * u + r;
            float w = (k < 6) ? W1[k * HH + h] : ((k == 6) ? b1[h] : 0.0f);
            A1[t][r] = f2bf(w);
        }
    }
    // L2: A2[mt*4+s] = W2^T: A[row=col -> n2=16mt+col][k=h=32s+8u+r]
    bf16x8 A2[16];
#pragma unroll
    for (int mt = 0; mt < 4; ++mt) {
#pragma unroll
        for (int s = 0; s < 4; ++s) {
            int n2 = 16 * mt + col;
#pragma unroll
            for (int r = 0; r < 8; ++r) {
                int h = 32 * s + 8 * u + r;
                A2[mt * 4 + s][r] = f2bf(W2[h * H2 + n2]);
            }
        }
    }
    // L3 constants: lane's n2 set is 16mt + 4u + q
    float b2c[16], w3c[16];
#pragma unroll
    for (int mt = 0; mt < 4; ++mt) {
#pragma unroll
        for (int q = 0; q < 4; ++q) {
            int n2 = 16 * mt + 4 * u + q;
            b2c[mt * 4 + q] = b2[n2];
            w3c[mt * 4 + q] = W3[n2];
        }
    }
    const float b3v = b3[0];

    __syncthreads();  // vertices staged (uniform: before any divergent loop)

    char* myh1 = (char*)&h1s[wid][0];
    const int gw = blockIdx.x * 4 + wid;
    const int nw = NBLK * 4;
    const f32x4 zero4 = {0.f, 0.f, 0.f, 0.f};

    for (int tt = gw; tt < NTILES; tt += nw) {
        const int t0 = tt * 16;
        const int b  = t0 / EE;       // EE % 16 == 0: tile never straddles b
        const int e0 = t0 - b * EE;

        // ---- build feats^T B-frag: only lane-group 0 carries k=0..7 ----
        bf16x8 bf = {0, 0, 0, 0, 0, 0, 0, 0};
        int iv = 0, jv = 0;
        if (u == 0) {
            const int e = e0 + col;
            // decode e -> (i,j), i<j, triangular row-major
            double tv = 2.0 * (double)VV - 1.0;
            int i = (int)((tv - sqrt(tv * tv - 8.0 * (double)e)) * 0.5);
            if (i < 0) i = 0;
            if (i > VV - 2) i = VV - 2;
            while (i > 0 && i * (2 * VV - i - 1) / 2 > e) --i;
            while ((i + 1) * (2 * VV - (i + 1) - 1) / 2 <= e) ++i;
            int j = e - i * (2 * VV - i - 1) / 2 + i + 1;
            iv = i; jv = j;
            const float* pvi = &sv[(b * VV + i) * 3];
            const float* pvj = &sv[(b * VV + j) * 3];
            bf[0] = f2bf(pvi[0]); bf[1] = f2bf(pvi[1]); bf[2] = f2bf(pvi[2]);
            bf[3] = f2bf(pvj[0]); bf[4] = f2bf(pvj[1]); bf[5] = f2bf(pvj[2]);
            bf[6] = f2bf(1.0f);   bf[7] = 0;            // k=6 carries bias
        }

        // ---- layer 1: 8 MFMA, relu+pack -> swizzled LDS bounce ----
#pragma unroll
        for (int t = 0; t < 8; ++t) {
            f32x4 d = __builtin_amdgcn_mfma_f32_16x16x32_bf16(A1[t], bf, zero4, 0, 0, 0);
            // lane holds h = 16t + 4u + r, edge = col
            unsigned short s0 = (unsigned short)f2bf(fmaxf(d[0], 0.f));
            unsigned short s1 = (unsigned short)f2bf(fmaxf(d[1], 0.f));
            unsigned short s2 = (unsigned short)f2bf(fmaxf(d[2], 0.f));
            unsigned short s3 = (unsigned short)f2bf(fmaxf(d[3], 0.f));
            uint2 p;
            p.x = (unsigned)s0 | ((unsigned)s1 << 16);
            p.y = (unsigned)s2 | ((unsigned)s3 << 16);
            int off = (col << 8) + ((16 * t + 4 * u) << 1);
            off ^= (col & 7) << 4;   // bank-spread swizzle (16B granular)
            *(uint2*)(myh1 + off) = p;
        }
        asm volatile("s_waitcnt lgkmcnt(0)" ::: "memory");  // writes visible wave-wide

        // ---- read back as L2 B-frags: B[k=h][edge]: k=32s+8u+r ----
        bf16x8 Bh[4];
#pragma unroll
        for (int s = 0; s < 4; ++s) {
            int off = (col << 8) + ((32 * s + 8 * u) << 1);
            off ^= (col & 7) << 4;
            Bh[s] = *(const bf16x8*)(myh1 + off);
        }
        asm volatile("s_waitcnt lgkmcnt(0)" ::: "memory");  // reads done before next-iter writes

        // ---- layer 2 (16 MFMA) + layer 3 fused ----
        float acc3 = 0.f;
#pragma unroll
        for (int mt = 0; mt < 4; ++mt) {
            f32x4 d2 = zero4;
#pragma unroll
            for (int s = 0; s < 4; ++s)
                d2 = __builtin_amdgcn_mfma_f32_16x16x32_bf16(A2[mt * 4 + s], Bh[s], d2, 0, 0, 0);
#pragma unroll
            for (int q = 0; q < 4; ++q) {
                float h2v = fmaxf(d2[q] + b2c[mt * 4 + q], 0.f);
                acc3 = fmaf(h2v, w3c[mt * 4 + q], acc3);
            }
        }
        // reduce partial dot across the 4 lane-groups (same edge = same lane&15)
        acc3 += __shfl_xor(acc3, 16);
        acc3 += __shfl_xor(acc3, 32);

        if (u == 0) {
            float prob = 1.0f / (1.0f + expf(-(acc3 + b3v)));
            out[t0 + col] = prob;
            if (b == 0) {
                const int e = e0 + col;
                float2 ij = make_float2((float)iv, (float)jv);
                *(float2*)(&out[BE + 2 * e]) = ij;
            }
        }
    }
}

extern "C" void kernel_launch(void* const* d_in, const int* in_sizes, int n_in,
                              void* d_out, int out_size, void* d_ws, size_t ws_size,
                              hipStream_t stream) {
    const float* vertices = (const float*)d_in[0];
    const float* W1 = (const float*)d_in[1];
    const float* b1 = (const float*)d_in[2];
    const float* W2 = (const float*)d_in[3];
    const float* b2 = (const float*)d_in[4];
    const float* W3 = (const float*)d_in[5];
    const float* b3 = (const float*)d_in[6];
    float* out = (float*)d_out;

    edge_mlp_mfma<<<NBLK, NTHR, 0, stream>>>(vertices, W1, b1, W2, b2, W3, b3, out);
}

// Round 3
// 151.113 us; speedup vs baseline: 4.8044x; 1.3724x over previous
//
#include <hip/hip_runtime.h>
#include <hip/hip_bf16.h>
#include <math.h>

#define BB 4
#define VV 1024
#define HH 128
#define H2 64
#define EE 523776               // V*(V-1)/2
#define BE (BB * EE)            // 2095104
#define TPB (EE / 16)           // 32736 tiles per batch (EE % 16 == 0)
#define NTILES (BE / 16)        // 130944
#define NTHR 256
#define NBLK 1024

typedef __attribute__((ext_vector_type(8))) short bf16x8;
typedef __attribute__((ext_vector_type(4))) float f32x4;

__device__ __forceinline__ short f2bf(float f) {
    __hip_bfloat16 h = __float2bfloat16(f);
    return *reinterpret_cast<short*>(&h);
}

// ---------------------------------------------------------------------------
// Round 3: no LDS, no barriers. The L1 MFMA's A-rows are PERMUTED so its C/D
// output layout coincides exactly with the L2 B-fragment layout:
//   A1 row m  ->  h = 32p + 8*(m>>2) + 4q + (m&3)
// giving lane(col,u) the h-values 32p+8u+{0..7} across a q-pair = its L2
// B-frag k-slots. relu+bf16-pack in registers, straight into L2 MFMA.
// b2 folded into the L2 accumulator init. b1 folded into feature slot k=6.
// ---------------------------------------------------------------------------
__global__ __launch_bounds__(NTHR, 3) void edge_mlp_mfma2(
    const float* __restrict__ vertices,  // [4,1024,3]
    const float* __restrict__ W1,        // [6,128]
    const float* __restrict__ b1,        // [128]
    const float* __restrict__ W2,        // [128,64]
    const float* __restrict__ b2,        // [64]
    const float* __restrict__ W3,        // [64]
    const float* __restrict__ b3,        // [1]
    float* __restrict__ out)             // [BE probs][2*EE indices-as-float]
{
    const int lane = threadIdx.x & 63;
    const int col  = lane & 15;          // edge slot (N dim everywhere)
    const int u    = lane >> 4;
    const int wid  = threadIdx.x >> 6;

    const f32x4 zero4 = {0.f, 0.f, 0.f, 0.f};

    // ---- persistent weight fragments (VGPRs) ----
    // L1: A1[p][q][r] = W1pad[k=8u+r][h(col)], h(col)=32p+8*(col>>2)+4q+(col&3)
    bf16x8 A1[4][2];
#pragma unroll
    for (int p = 0; p < 4; ++p)
#pragma unroll
        for (int q = 0; q < 2; ++q) {
            const int h = 32 * p + 8 * (col >> 2) + 4 * q + (col & 3);
#pragma unroll
            for (int r = 0; r < 8; ++r) {
                const int k = 8 * u + r;
                float w = 0.0f;
                if (k < 6)       w = W1[k * HH + h];
                else if (k == 6) w = b1[h];
                A1[p][q][r] = f2bf(w);
            }
        }

    // L2: A2[mt][p][r] = W2[h=32p+8u+r][n2=16mt+col]
    bf16x8 A2[4][4];
#pragma unroll
    for (int mt = 0; mt < 4; ++mt)
#pragma unroll
        for (int p = 0; p < 4; ++p) {
            const int n2 = 16 * mt + col;
#pragma unroll
            for (int r = 0; r < 8; ++r) {
                const int h = 32 * p + 8 * u + r;
                A2[mt][p][r] = f2bf(W2[h * H2 + n2]);
            }
        }

    // L3 constants; b2 as L2 accumulator init (C-in = bias)
    f32x4 cinit[4];
    float w3c[16];
#pragma unroll
    for (int mt = 0; mt < 4; ++mt)
#pragma unroll
        for (int q = 0; q < 4; ++q) {
            const int n2 = 16 * mt + 4 * u + q;
            cinit[mt][q]    = b2[n2];
            w3c[mt * 4 + q] = W3[n2];
        }
    const float b3v = b3[0];

    const int gw = blockIdx.x * 4 + wid;

    for (int tt = gw; tt < NTILES; tt += NBLK * 4) {
        const int b  = tt / TPB;
        const int e0 = (tt - b * TPB) * 16;
        const int e  = e0 + col;

        // ---- decode e -> (i,j): reverse-triangular, exact f32 (8r+1 < 2^23) ----
        const int rr = EE - 1 - e;
        const float sq = sqrtf((float)(8 * rr + 1));
        int m = (int)(0.5f * (sq - 1.0f));
        if ((m + 1) * (m + 2) / 2 <= rr) ++m;   // one-step fixups cover sqrt ulp
        if (m * (m + 1) / 2 > rr) --m;
        const int pp = rr - m * (m + 1) / 2;
        const int iv = VV - 2 - m;
        const int jv = VV - 1 - pp;

        // ---- feature B-frag: k=8u+r; only u==0 carries data (k=0..6) ----
        bf16x8 bf = {0, 0, 0, 0, 0, 0, 0, 0};
        if (u == 0) {
            const float* pvi = vertices + (b * VV + iv) * 3;
            const float* pvj = vertices + (b * VV + jv) * 3;
            bf[0] = f2bf(pvi[0]); bf[1] = f2bf(pvi[1]); bf[2] = f2bf(pvi[2]);
            bf[3] = f2bf(pvj[0]); bf[4] = f2bf(pvj[1]); bf[5] = f2bf(pvj[2]);
            bf[6] = f2bf(1.0f);                       // k=6 carries b1
        }

        f32x4 d2_0 = cinit[0], d2_1 = cinit[1], d2_2 = cinit[2], d2_3 = cinit[3];

#pragma unroll
        for (int p = 0; p < 4; ++p) {
            f32x4 dA = __builtin_amdgcn_mfma_f32_16x16x32_bf16(A1[p][0], bf, zero4, 0, 0, 0);
            f32x4 dB = __builtin_amdgcn_mfma_f32_16x16x32_bf16(A1[p][1], bf, zero4, 0, 0, 0);
            // lane(col,u) now holds h = 32p+8u+{0..3} (dA) and +{4..7} (dB):
            // exactly its L2 B-frag slots for k-tile p. relu + pack in-register.
            bf16x8 Bh;
            Bh[0] = f2bf(fmaxf(dA[0], 0.f)); Bh[1] = f2bf(fmaxf(dA[1], 0.f));
            Bh[2] = f2bf(fmaxf(dA[2], 0.f)); Bh[3] = f2bf(fmaxf(dA[3], 0.f));
            Bh[4] = f2bf(fmaxf(dB[0], 0.f)); Bh[5] = f2bf(fmaxf(dB[1], 0.f));
            Bh[6] = f2bf(fmaxf(dB[2], 0.f)); Bh[7] = f2bf(fmaxf(dB[3], 0.f));
            d2_0 = __builtin_amdgcn_mfma_f32_16x16x32_bf16(A2[0][p], Bh, d2_0, 0, 0, 0);
            d2_1 = __builtin_amdgcn_mfma_f32_16x16x32_bf16(A2[1][p], Bh, d2_1, 0, 0, 0);
            d2_2 = __builtin_amdgcn_mfma_f32_16x16x32_bf16(A2[2][p], Bh, d2_2, 0, 0, 0);
            d2_3 = __builtin_amdgcn_mfma_f32_16x16x32_bf16(A2[3][p], Bh, d2_3, 0, 0, 0);
        }

        // ---- layer 3: relu(d2)·W3, reduce across u, sigmoid ----
        float acc = 0.f;
#pragma unroll
        for (int q = 0; q < 4; ++q) acc = fmaf(fmaxf(d2_0[q], 0.f), w3c[q],      acc);
#pragma unroll
        for (int q = 0; q < 4; ++q) acc = fmaf(fmaxf(d2_1[q], 0.f), w3c[4 + q],  acc);
#pragma unroll
        for (int q = 0; q < 4; ++q) acc = fmaf(fmaxf(d2_2[q], 0.f), w3c[8 + q],  acc);
#pragma unroll
        for (int q = 0; q < 4; ++q) acc = fmaf(fmaxf(d2_3[q], 0.f), w3c[12 + q], acc);

        acc += __shfl_xor(acc, 16);
        acc += __shfl_xor(acc, 32);

        if (u == 0) {
            const float x = acc + b3v;
            const float prob = __builtin_amdgcn_rcpf(1.0f + __expf(-x));
            out[tt * 16 + col] = prob;           // tt*16 == b*EE + e0
            if (b == 0) {
                *(float2*)(&out[BE + 2 * e]) = make_float2((float)iv, (float)jv);
            }
        }
    }
}

extern "C" void kernel_launch(void* const* d_in, const int* in_sizes, int n_in,
                              void* d_out, int out_size, void* d_ws, size_t ws_size,
                              hipStream_t stream) {
    const float* vertices = (const float*)d_in[0];
    const float* W1 = (const float*)d_in[1];
    const float* b1 = (const float*)d_in[2];
    const float* W2 = (const float*)d_in[3];
    const float* b2 = (const float*)d_in[4];
    const float* W3 = (const float*)d_in[5];
    const float* b3 = (const float*)d_in[6];
    float* out = (float*)d_out;

    edge_mlp_mfma2<<<NBLK, NTHR, 0, stream>>>(vertices, W1, b1, W2, b2, W3, b3, out);
}